// Round 6
// baseline (23.672 us; speedup 1.0000x reference)
//
#include <hip/hip_runtime.h>

typedef __attribute__((ext_vector_type(8))) short bf16x8;
typedef __attribute__((ext_vector_type(4))) float f32x4;
typedef __attribute__((ext_vector_type(4))) short s16x4;

__device__ __forceinline__ unsigned short f2bf(float f) {
    unsigned int u = __builtin_bit_cast(unsigned int, f);
    u += 0x7fffu + ((u >> 16) & 1u);   // round-to-nearest-even
    return (unsigned short)(u >> 16);
}
__device__ __forceinline__ float bf2f(unsigned short h) {
    return __builtin_bit_cast(float, ((unsigned int)h) << 16);
}

// Kernel 1: A[i][j] = (i==j) ? 0 : sum_d w[i,field[j],d] * w[j,field[i],d]
// Symmetric, bit-identical across the diagonal. Packed bf16 in MFMA fragment
// order: apk[((kt*8+nt)*64+lane)*8+r] <-> A[kt*32+(lane>>4)*8+r][nt*16+(lane&15)].
// By symmetry the same packing is the A-operand fragment (row-block nt, k-block kt).
__global__ void build_A_kernel(const float* __restrict__ w, const int* __restrict__ field,
                               unsigned short* __restrict__ apk) {
    int idx = blockIdx.x * 128 + threadIdx.x;   // 0..16383
    int i = idx >> 7, j = idx & 127;
    const float* wi = w + (i * 16 + field[j]) * 16;
    const float* wj = w + (j * 16 + field[i]) * 16;
    float s = 0.f;
#pragma unroll
    for (int d = 0; d < 16; ++d) s += wi[d] * wj[d];
    if (i == j) s = 0.f;
    int kt = i >> 5, g = (i >> 3) & 3, r = i & 7;
    int nt = j >> 4, c = j & 15;
    apk[((kt * 8 + nt) * 64 + (g * 16 + c)) * 8 + r] = f2bf(s);
}

// Kernel 2 (R3-proven structure, i-split across waves):
// wave wv computes Y[m][i] for i in [wv*32, wv*32+32) for ALL 64 rows m of the
// tile, accumulates partial dots sum_i X[m][i]*Y[m][i], combines across waves
// via LDS. Per-wave A-fragments: only q = wv*2, wv*2+1 (32 VGPR) -> 3 blocks/CU.
__global__ __launch_bounds__(256, 3)
void ffm_kernel(const float* __restrict__ x, const unsigned short* __restrict__ apk,
                float* __restrict__ out, int nTiles, int tilesPerWG) {
    __shared__ __align__(16) unsigned short Xl[2][64 * 128];  // 2 x 16 KiB bf16, swizzled
    __shared__ float psum[4][64];                             // per-wave partials
    const int tid  = threadIdx.x;
    const int lane = tid & 63;
    const int wv   = tid >> 6;
    const int g    = lane >> 4;
    const int c    = lane & 15;

    const int tile0 = blockIdx.x * tilesPerWG;
    if (tile0 >= nTiles) return;

    // Each wave caches only ITS i-range fragments (q = wv*2+qq): 8 frags = 32 VGPR.
    bf16x8 bfrag[4][2];
#pragma unroll
    for (int kt = 0; kt < 4; ++kt)
#pragma unroll
        for (int qq = 0; qq < 2; ++qq) {
            int q = wv * 2 + qq;
            bfrag[kt][qq] = *reinterpret_cast<const bf16x8*>(apk + ((kt * 8 + q) * 64 + lane) * 8);
        }

    // Prefetch first tile (plain loads: x is L3-resident across replays; no NT hint).
    f32x4 xr[8];
    {
        const f32x4* src = reinterpret_cast<const f32x4*>(x) + (size_t)tile0 * 2048;
#pragma unroll
        for (int i = 0; i < 8; ++i) xr[i] = src[i * 256 + tid];
    }

    int buf = 0;
    for (int t = 0; t < tilesPerWG; ++t) {
        int tile = tile0 + t;
        if (tile >= nTiles) break;

        // Stage regs -> LDS bf16, XOR swizzle (short idx ^= (row&7)<<3).
#pragma unroll
        for (int i = 0; i < 8; ++i) {
            int row = i * 8 + (tid >> 5);
            int k   = (tid & 31) * 4;
            int sw  = row * 128 + (k ^ ((row & 7) << 3));
            s16x4 s4;
            s4.x = (short)f2bf(xr[i][0]);
            s4.y = (short)f2bf(xr[i][1]);
            s4.z = (short)f2bf(xr[i][2]);
            s4.w = (short)f2bf(xr[i][3]);
            *reinterpret_cast<s16x4*>(&Xl[buf][sw]) = s4;
        }
        // Prefetch next tile before the barrier (in flight across compute).
        if (t + 1 < tilesPerWG && tile + 1 < nTiles) {
            const f32x4* src = reinterpret_cast<const f32x4*>(x) + (size_t)(tile + 1) * 2048;
#pragma unroll
            for (int i = 0; i < 8; ++i) xr[i] = src[i * 256 + tid];
        }
        __syncthreads();

        // acc[mt][qq][r] = Y[m = mt*16+c][i = (wv*2+qq)*16 + g*4 + r]
        f32x4 acc[4][2];
#pragma unroll
        for (int mt = 0; mt < 4; ++mt)
#pragma unroll
            for (int qq = 0; qq < 2; ++qq) acc[mt][qq] = (f32x4){0.f, 0.f, 0.f, 0.f};
#pragma unroll
        for (int kt = 0; kt < 4; ++kt)
#pragma unroll
            for (int mt = 0; mt < 4; ++mt) {
                int row = mt * 16 + c;
                int k0  = kt * 32 + g * 8;
                bf16x8 xa = *reinterpret_cast<const bf16x8*>(
                    &Xl[buf][row * 128 + (k0 ^ ((row & 7) << 3))]);
#pragma unroll
                for (int qq = 0; qq < 2; ++qq)
                    acc[mt][qq] = __builtin_amdgcn_mfma_f32_16x16x32_bf16(
                        bfrag[kt][qq], xa, acc[mt][qq], 0, 0, 0);
            }

        // Per-wave partial dots over its 32 i's, for all 64 m's.
        float sacc[4] = {0.f, 0.f, 0.f, 0.f};
#pragma unroll
        for (int mt = 0; mt < 4; ++mt) {
            int row  = mt * 16 + c;
            int base = row * 128;
            int xv   = (row & 7) << 3;
#pragma unroll
            for (int qq = 0; qq < 2; ++qq) {
                int ix = (wv * 2 + qq) * 16 + g * 4;
                s16x4 xs = *reinterpret_cast<const s16x4*>(&Xl[buf][base + (ix ^ xv)]);
                sacc[mt] += bf2f((unsigned short)xs.x) * acc[mt][qq][0]
                          + bf2f((unsigned short)xs.y) * acc[mt][qq][1]
                          + bf2f((unsigned short)xs.z) * acc[mt][qq][2]
                          + bf2f((unsigned short)xs.w) * acc[mt][qq][3];
            }
        }
#pragma unroll
        for (int mt = 0; mt < 4; ++mt) {
            sacc[mt] += __shfl_xor(sacc[mt], 16, 64);
            sacc[mt] += __shfl_xor(sacc[mt], 32, 64);
        }
        if (g == 0) {
#pragma unroll
            for (int mt = 0; mt < 4; ++mt) psum[wv][mt * 16 + c] = sacc[mt];
        }
        __syncthreads();
        if (tid < 64)
            out[(size_t)tile * 64 + tid] =
                0.5f * (psum[0][tid] + psum[1][tid] + psum[2][tid] + psum[3][tid]);

        buf ^= 1;
    }
}

extern "C" void kernel_launch(void* const* d_in, const int* in_sizes, int n_in,
                              void* d_out, int out_size, void* d_ws, size_t ws_size,
                              hipStream_t stream) {
    const float* x     = (const float*)d_in[0];
    const float* w     = (const float*)d_in[1];
    const int*   field = (const int*)d_in[2];
    float* outp        = (float*)d_out;
    unsigned short* apk = (unsigned short*)d_ws;   // 32 KiB packed A

    int B = in_sizes[0] / 128;
    build_A_kernel<<<128, 128, 0, stream>>>(w, field, apk);

    int nTiles = B / 64;                   // 2048 for B=131072
    const int TPW = 3;
    int grid = (nTiles + TPW - 1) / TPW;   // 683 blocks -> all resident at 3/CU
    ffm_kernel<<<grid, 256, 0, stream>>>(x, apk, outp, nTiles, TPW);
}

// Round 7
// 22.370 us; speedup vs baseline: 1.0582x; 1.0582x over previous
//
#include <hip/hip_runtime.h>

typedef __attribute__((ext_vector_type(8))) short bf16x8;
typedef __attribute__((ext_vector_type(4))) float f32x4;
typedef __attribute__((ext_vector_type(4))) short s16x4;

__device__ __forceinline__ unsigned short f2bf(float f) {
    unsigned int u = __builtin_bit_cast(unsigned int, f);
    u += 0x7fffu + ((u >> 16) & 1u);   // round-to-nearest-even
    return (unsigned short)(u >> 16);
}
__device__ __forceinline__ float bf2f(unsigned short h) {
    return __builtin_bit_cast(float, ((unsigned int)h) << 16);
}

// Kernel 1: A[i][j] = (i==j) ? 0 : sum_d w[i,field[j],d] * w[j,field[i],d]
// Symmetric, bit-identical across the diagonal. Packed bf16 in MFMA fragment
// order: apk[((kt*8+nt)*64+lane)*8+r] <-> A[kt*32+(lane>>4)*8+r][nt*16+(lane&15)].
// By symmetry the same packing is the A-operand fragment (row-block nt, k-block kt).
__global__ void build_A_kernel(const float* __restrict__ w, const int* __restrict__ field,
                               unsigned short* __restrict__ apk) {
    int idx = blockIdx.x * 128 + threadIdx.x;   // 0..16383
    int i = idx >> 7, j = idx & 127;
    const float* wi = w + (i * 16 + field[j]) * 16;
    const float* wj = w + (j * 16 + field[i]) * 16;
    float s = 0.f;
#pragma unroll
    for (int d = 0; d < 16; ++d) s += wi[d] * wj[d];
    if (i == j) s = 0.f;
    int kt = i >> 5, g = (i >> 3) & 3, r = i & 7;
    int nt = j >> 4, c = j & 15;
    apk[((kt * 8 + nt) * 64 + (g * 16 + c)) * 8 + r] = f2bf(s);
}

// Kernel 2 (R3-proven math/layout; schedule fix: prefetch issued AFTER the
// barrier so the barrier's vmcnt(0) drain never waits on next-tile loads —
// loads(t+1) stay in flight across compute(t)+epilogue(t), consumed by the
// natural s_waitcnt at stage(t+1)).
__global__ __launch_bounds__(256, 2)
void ffm_kernel(const float* __restrict__ x, const unsigned short* __restrict__ apk,
                float* __restrict__ out, int nTiles, int tilesPerWG) {
    __shared__ __align__(16) unsigned short Xl[2][64 * 128];  // 2 x 16 KiB bf16, swizzled
    const int tid  = threadIdx.x;
    const int lane = tid & 63;
    const int wv   = tid >> 6;     // wave 0..3 owns rows [wv*16, wv*16+16)
    const int g    = lane >> 4;
    const int c    = lane & 15;

    const int tile0 = blockIdx.x * tilesPerWG;
    if (tile0 >= nTiles) return;

    // Issue first-tile x loads FIRST (HBM busy while bfrag L2 reads happen).
    f32x4 xr[8];
    {
        const f32x4* src = reinterpret_cast<const f32x4*>(x) + (size_t)tile0 * 2048;
#pragma unroll
        for (int i = 0; i < 8; ++i) xr[i] = src[i * 256 + tid];
    }

    // Cache the whole interaction matrix as MFMA fragments in registers (128 VGPR).
    bf16x8 bfrag[4][8];
#pragma unroll
    for (int kt = 0; kt < 4; ++kt)
#pragma unroll
        for (int nt = 0; nt < 8; ++nt)
            bfrag[kt][nt] = *reinterpret_cast<const bf16x8*>(apk + ((kt * 8 + nt) * 64 + lane) * 8);

    const int myrow = wv * 16 + c;
    const int rowbase = myrow * 128;
    const int xv = (myrow & 7) << 3;

    int buf = 0;
    for (int t = 0; t < tilesPerWG; ++t) {
        int tile = tile0 + t;
        if (tile >= nTiles) break;

        // Stage regs -> LDS bf16, XOR swizzle (short idx ^= (row&7)<<3).
        // (Natural s_waitcnt on xr sits here, not at the barrier.)
#pragma unroll
        for (int i = 0; i < 8; ++i) {
            int row = i * 8 + (tid >> 5);
            int k   = (tid & 31) * 4;
            int sw  = row * 128 + (k ^ ((row & 7) << 3));
            s16x4 s4;
            s4.x = (short)f2bf(xr[i][0]);
            s4.y = (short)f2bf(xr[i][1]);
            s4.z = (short)f2bf(xr[i][2]);
            s4.w = (short)f2bf(xr[i][3]);
            *reinterpret_cast<s16x4*>(&Xl[buf][sw]) = s4;
        }
        __syncthreads();   // nothing outstanding in vmem here -> drain is free

        // NOW issue next-tile loads: in flight across compute+epilogue.
        if (t + 1 < tilesPerWG && tile + 1 < nTiles) {
            const f32x4* src = reinterpret_cast<const f32x4*>(x) + (size_t)(tile + 1) * 2048;
#pragma unroll
            for (int i = 0; i < 8; ++i) xr[i] = src[i * 256 + tid];
        }

        // Yt = A(128x128) * X^T(128x16): acc[q] = Y[myrow][q*16 + g*4 + r].
        f32x4 acc[8];
#pragma unroll
        for (int q = 0; q < 8; ++q) acc[q] = (f32x4){0.f, 0.f, 0.f, 0.f};
#pragma unroll
        for (int kt = 0; kt < 4; ++kt) {
            int k0 = kt * 32 + g * 8;   // B-operand: col=c (-> row myrow), k-slots g*8+r
            bf16x8 xa = *reinterpret_cast<const bf16x8*>(
                &Xl[buf][rowbase + (k0 ^ xv)]);
#pragma unroll
            for (int q = 0; q < 8; ++q)
                acc[q] = __builtin_amdgcn_mfma_f32_16x16x32_bf16(bfrag[kt][q], xa, acc[q], 0, 0, 0);
        }

        // Epilogue: sacc = sum over this lane's 32 i's of X[m][i]*Y[m][i].
        float sacc = 0.f;
#pragma unroll
        for (int q = 0; q < 8; ++q) {
            int ix = q * 16 + g * 4;
            s16x4 xs = *reinterpret_cast<const s16x4*>(&Xl[buf][rowbase + (ix ^ xv)]);
            sacc += bf2f((unsigned short)xs.x) * acc[q][0];
            sacc += bf2f((unsigned short)xs.y) * acc[q][1];
            sacc += bf2f((unsigned short)xs.z) * acc[q][2];
            sacc += bf2f((unsigned short)xs.w) * acc[q][3];
        }
        sacc += __shfl_xor(sacc, 16, 64);
        sacc += __shfl_xor(sacc, 32, 64);
        if (g == 0) out[(size_t)tile * 64 + myrow] = 0.5f * sacc;

        buf ^= 1;
    }
}

extern "C" void kernel_launch(void* const* d_in, const int* in_sizes, int n_in,
                              void* d_out, int out_size, void* d_ws, size_t ws_size,
                              hipStream_t stream) {
    const float* x     = (const float*)d_in[0];
    const float* w     = (const float*)d_in[1];
    const int*   field = (const int*)d_in[2];
    float* outp        = (float*)d_out;
    unsigned short* apk = (unsigned short*)d_ws;   // 32 KiB packed A

    int B = in_sizes[0] / 128;
    build_A_kernel<<<128, 128, 0, stream>>>(w, field, apk);

    int nTiles = B / 64;                   // 2048 for B=131072
    const int TPW = 4;
    int grid = (nTiles + TPW - 1) / TPW;   // 512 = exactly 2 blocks/CU
    ffm_kernel<<<grid, 256, 0, stream>>>(x, apk, outp, nTiles, TPW);
}